// Round 1
// baseline (752.692 us; speedup 1.0000x reference)
//
#include <hip/hip_runtime.h>
#include <hip/hip_fp16.h>
#include <math.h>

// Problem constants
#define EXPERTS 8
#define DDIM 2048       // model dim
#define HDIM 2048       // expert hidden dim (gate_up has 2*HDIM cols)
#define NTOK 4096       // B*L
#define NPAIR 8192      // NTOK*K
#define MAXSLOT 9216    // padded slot capacity (8192 + 8*127 rounded up)
#define MAXTILE 72      // max sum of ceil(cnt_e/128)

typedef _Float16 f16;
typedef __attribute__((ext_vector_type(8))) _Float16 f16x8;
typedef __attribute__((ext_vector_type(4))) _Float16 f16x4;
typedef __attribute__((ext_vector_type(4))) float f32x4;

// ---- workspace layout (bytes) ----
#define GUPT_OFF   0u                       // f16 [E][2H][D]   134217728
#define DWNT_OFF   134217728u               // f16 [E][D][H]     67108864
#define XF_OFF     201326592u               // f16 [NTOK][D]     16777216
#define ACT_OFF    218103808u               // f16 [MAXSLOT][H]  37748736
#define CTRL_OFF   255852544u
// ctrl block (ints/floats):
//  [0 .. 9216)      slot_tok
//  [9216 .. 18432)  slot_w (float)
//  [18432..18440)   cnt
//  [18440..18448)   cursor
//  [18448..18456)   pad_off
//  [18456..18528)   tile_e
//  [18528..18600)   tile_r0
//  [18600]          n_tiles
//  [18601]          is32 flag
#define CTRL_INTS 18608

__device__ __forceinline__ void gload_lds16(const void* g, void* l) {
  __builtin_amdgcn_global_load_lds(
      (const __attribute__((address_space(1))) unsigned int*)g,
      (__attribute__((address_space(3))) unsigned int*)l,
      16, 0, 0);
}

// Detect int32 vs int64 expert_indices: for int64 (values 0..7, LE) every odd
// 32-bit word is 0; for int32 random data some odd word is nonzero.
__global__ void k_detect(const int* __restrict__ w, int* flag) {
  int i = blockIdx.x * blockDim.x + threadIdx.x;  // 4096 threads
  if (i < NPAIR / 2 && w[2 * i + 1] != 0) atomicOr(flag, 1);
}

__device__ __forceinline__ int expert_of(const int* idx, int is32, int p) {
  return is32 ? idx[p] : idx[2 * p];
}

__global__ void k_count(const int* __restrict__ idx, const int* __restrict__ flag,
                        int* cnt) {
  int p = blockIdx.x * blockDim.x + threadIdx.x;
  if (p < NPAIR) atomicAdd(&cnt[expert_of(idx, *flag, p)], 1);
}

__global__ void k_plan(const int* __restrict__ cnt, int* cursor, int* pad_off,
                       int* tile_e, int* tile_r0, int* n_tiles) {
  if (blockIdx.x == 0 && threadIdx.x == 0) {
    int off = 0, nt = 0;
    for (int e = 0; e < EXPERTS; ++e) {
      pad_off[e] = off;
      cursor[e] = off;
      int t = (cnt[e] + 127) >> 7;
      for (int i = 0; i < t; ++i) { tile_e[nt] = e; tile_r0[nt] = off + i * 128; ++nt; }
      off += t * 128;
    }
    *n_tiles = nt;
  }
}

__global__ void k_assign(const int* __restrict__ idx, const int* __restrict__ flag,
                         const float* __restrict__ wts, const float* __restrict__ scale,
                         int* cursor, int* slot_tok, float* slot_w) {
  int p = blockIdx.x * blockDim.x + threadIdx.x;
  if (p < NPAIR) {
    int e = expert_of(idx, *flag, p);
    int pos = atomicAdd(&cursor[e], 1);
    slot_tok[pos] = p >> 1;                 // token index
    slot_w[pos] = wts[p] * scale[e];        // combine weight with scale folded in
  }
}

__global__ void k_cvt_x(const float* __restrict__ in, f16* __restrict__ out) {
  int i = blockIdx.x * blockDim.x + threadIdx.x;  // one float4 per thread
  float4 v = ((const float4*)in)[i];
  f16x4 o = {(f16)v.x, (f16)v.y, (f16)v.z, (f16)v.w};
  ((f16x4*)out)[i] = o;
}

// fp32 [R][C] -> f16 [C][R], per expert (blockIdx.z)
__global__ void k_transpose(const float* __restrict__ in, f16* __restrict__ out,
                            int R, int C) {
  __shared__ float t[32][33];
  const size_t base = (size_t)blockIdx.z * R * C;
  const float* ip = in + base;
  f16* op = out + base;
  int c0 = blockIdx.x * 32, r0 = blockIdx.y * 32;
  int tx = threadIdx.x, ty = threadIdx.y;
#pragma unroll
  for (int i = 0; i < 32; i += 8)
    t[ty + i][tx] = ip[(size_t)(r0 + ty + i) * C + c0 + tx];
  __syncthreads();
#pragma unroll
  for (int i = 0; i < 32; i += 8)
    op[(size_t)(c0 + ty + i) * R + r0 + tx] = (f16)t[tx][ty + i];
}

// GEMM1 (fused gate+up+gelu): act[slot][j] = gelu(h_g) * h_u
// A: gathered x rows (f16 [NTOK][D]); B: gup_t (f16 [E][2H][D], K-contig rows)
__global__ __launch_bounds__(256) void k_gemm1(
    const f16* __restrict__ xf, const f16* __restrict__ gup_t,
    const int* __restrict__ slot_tok,
    const int* __restrict__ tile_e, const int* __restrict__ tile_r0,
    const int* __restrict__ n_tiles,
    f16* __restrict__ act) {
  if ((int)blockIdx.x >= *n_tiles) return;
  const int e = tile_e[blockIdx.x];
  const int row0 = tile_r0[blockIdx.x];
  const int j0 = blockIdx.y * 128;  // gate column strip; up strip at +2048

  __shared__ __align__(16) f16 lA[2][128 * 32];
  __shared__ __align__(16) f16 lBg[2][128 * 32];
  __shared__ __align__(16) f16 lBu[2][128 * 32];

  const int tid = threadIdx.x;
  const int lane = tid & 63;
  const int wv = tid >> 6;
  const int wrow = (wv >> 1) * 64;
  const int wcol = (wv & 1) * 64;

  // staging geometry: lane covers 16B chunk (lane&3) of row wv*16+(lane>>2),
  // issues 0/1 are rows +0 / +64. Swizzle on SOURCE chunk (linear LDS dest).
  const int r0i = wv * 16 + (lane >> 2);
  const int csw = (lane & 3) ^ (r0i & 3);
  const size_t srcoff = (size_t)csw * 8;

  const f16* aSrc0 = xf + (size_t)slot_tok[row0 + r0i] * DDIM + srcoff;
  const f16* aSrc1 = xf + (size_t)slot_tok[row0 + r0i + 64] * DDIM + srcoff;
  const f16* gSrc0 = gup_t + ((size_t)e * 4096 + j0 + r0i) * DDIM + srcoff;
  const f16* gSrc1 = gSrc0 + (size_t)64 * DDIM;
  const f16* uSrc0 = gup_t + ((size_t)e * 4096 + 2048 + j0 + r0i) * DDIM + srcoff;
  const f16* uSrc1 = uSrc0 + (size_t)64 * DDIM;

  const int ldst0 = wv * 512 + lane * 8;  // f16 units; issue1 at +2048

  f32x4 ag[4][4], au[4][4];
#pragma unroll
  for (int i = 0; i < 4; ++i)
#pragma unroll
    for (int j = 0; j < 4; ++j) {
      ag[i][j] = (f32x4){0.f, 0.f, 0.f, 0.f};
      au[i][j] = (f32x4){0.f, 0.f, 0.f, 0.f};
    }

  auto stage = [&](int buf, int kb) {
    const size_t ko = (size_t)kb * 32;
    f16* la = &lA[buf][0];
    f16* lg = &lBg[buf][0];
    f16* lu = &lBu[buf][0];
    gload_lds16(aSrc0 + ko, la + ldst0);
    gload_lds16(aSrc1 + ko, la + ldst0 + 2048);
    gload_lds16(gSrc0 + ko, lg + ldst0);
    gload_lds16(gSrc1 + ko, lg + ldst0 + 2048);
    gload_lds16(uSrc0 + ko, lu + ldst0);
    gload_lds16(uSrc1 + ko, lu + ldst0 + 2048);
  };

  stage(0, 0);
  __syncthreads();

  const int fr = lane & 15, fc = lane >> 4;
  const int NKB = DDIM / 32;
  for (int kb = 0; kb < NKB; ++kb) {
    const int cur = kb & 1;
    if (kb + 1 < NKB) stage(cur ^ 1, kb + 1);
    f16x8 fa[4], fg[4], fu[4];
#pragma unroll
    for (int mi = 0; mi < 4; ++mi) {
      int r = wrow + mi * 16 + fr;
      fa[mi] = *(const f16x8*)&lA[cur][r * 32 + ((fc ^ (r & 3)) << 3)];
    }
#pragma unroll
    for (int ni = 0; ni < 4; ++ni) {
      int r = wcol + ni * 16 + fr;
      fg[ni] = *(const f16x8*)&lBg[cur][r * 32 + ((fc ^ (r & 3)) << 3)];
      fu[ni] = *(const f16x8*)&lBu[cur][r * 32 + ((fc ^ (r & 3)) << 3)];
    }
#pragma unroll
    for (int mi = 0; mi < 4; ++mi)
#pragma unroll
      for (int ni = 0; ni < 4; ++ni) {
        ag[mi][ni] = __builtin_amdgcn_mfma_f32_16x16x32_f16(fa[mi], fg[ni], ag[mi][ni], 0, 0, 0);
        au[mi][ni] = __builtin_amdgcn_mfma_f32_16x16x32_f16(fa[mi], fu[ni], au[mi][ni], 0, 0, 0);
      }
    __syncthreads();
  }

  // epilogue: exact gelu(gate)*up -> act (f16)
  const int erow = wrow + ((lane >> 4) << 2);
  const int ecol = wcol + (lane & 15);
#pragma unroll
  for (int mi = 0; mi < 4; ++mi)
#pragma unroll
    for (int ni = 0; ni < 4; ++ni)
#pragma unroll
      for (int r = 0; r < 4; ++r) {
        int slot = row0 + erow + mi * 16 + r;
        int col = j0 + ecol + ni * 16;
        float g = ag[mi][ni][r];
        float u = au[mi][ni][r];
        float a = 0.5f * g * (1.0f + erff(g * 0.70710678118654752f)) * u;
        act[(size_t)slot * HDIM + col] = (f16)a;
      }
}

// GEMM2: y[slot][d] = act[slot] @ down_t[e][d][:]; atomicAdd(w * y) into out[token]
__global__ __launch_bounds__(256) void k_gemm2(
    const f16* __restrict__ act, const f16* __restrict__ down_t,
    const int* __restrict__ slot_tok, const float* __restrict__ slot_w,
    const int* __restrict__ tile_e, const int* __restrict__ tile_r0,
    const int* __restrict__ n_tiles,
    float* __restrict__ out) {
  if ((int)blockIdx.x >= *n_tiles) return;
  const int e = tile_e[blockIdx.x];
  const int row0 = tile_r0[blockIdx.x];
  const int j0 = blockIdx.y * 128;  // output (D) column strip

  __shared__ __align__(16) f16 lA[2][128 * 32];
  __shared__ __align__(16) f16 lB[2][128 * 32];

  const int tid = threadIdx.x;
  const int lane = tid & 63;
  const int wv = tid >> 6;
  const int wrow = (wv >> 1) * 64;
  const int wcol = (wv & 1) * 64;

  const int r0i = wv * 16 + (lane >> 2);
  const int csw = (lane & 3) ^ (r0i & 3);
  const size_t srcoff = (size_t)csw * 8;

  const f16* aSrc0 = act + (size_t)(row0 + r0i) * HDIM + srcoff;
  const f16* aSrc1 = aSrc0 + (size_t)64 * HDIM;
  const f16* bSrc0 = down_t + ((size_t)e * DDIM + j0 + r0i) * HDIM + srcoff;
  const f16* bSrc1 = bSrc0 + (size_t)64 * HDIM;

  const int ldst0 = wv * 512 + lane * 8;

  f32x4 acc[4][4];
#pragma unroll
  for (int i = 0; i < 4; ++i)
#pragma unroll
    for (int j = 0; j < 4; ++j) acc[i][j] = (f32x4){0.f, 0.f, 0.f, 0.f};

  auto stage = [&](int buf, int kb) {
    const size_t ko = (size_t)kb * 32;
    f16* la = &lA[buf][0];
    f16* lb = &lB[buf][0];
    gload_lds16(aSrc0 + ko, la + ldst0);
    gload_lds16(aSrc1 + ko, la + ldst0 + 2048);
    gload_lds16(bSrc0 + ko, lb + ldst0);
    gload_lds16(bSrc1 + ko, lb + ldst0 + 2048);
  };

  stage(0, 0);
  __syncthreads();

  const int fr = lane & 15, fc = lane >> 4;
  const int NKB = HDIM / 32;
  for (int kb = 0; kb < NKB; ++kb) {
    const int cur = kb & 1;
    if (kb + 1 < NKB) stage(cur ^ 1, kb + 1);
    f16x8 fa[4], fb[4];
#pragma unroll
    for (int mi = 0; mi < 4; ++mi) {
      int r = wrow + mi * 16 + fr;
      fa[mi] = *(const f16x8*)&lA[cur][r * 32 + ((fc ^ (r & 3)) << 3)];
    }
#pragma unroll
    for (int ni = 0; ni < 4; ++ni) {
      int r = wcol + ni * 16 + fr;
      fb[ni] = *(const f16x8*)&lB[cur][r * 32 + ((fc ^ (r & 3)) << 3)];
    }
#pragma unroll
    for (int mi = 0; mi < 4; ++mi)
#pragma unroll
      for (int ni = 0; ni < 4; ++ni)
        acc[mi][ni] = __builtin_amdgcn_mfma_f32_16x16x32_f16(fa[mi], fb[ni], acc[mi][ni], 0, 0, 0);
    __syncthreads();
  }

  const int erow = wrow + ((lane >> 4) << 2);
  const int ecol = j0 + wcol + (lane & 15);
#pragma unroll
  for (int mi = 0; mi < 4; ++mi)
#pragma unroll
    for (int r = 0; r < 4; ++r) {
      int slot = row0 + erow + mi * 16 + r;
      float w = slot_w[slot];
      if (w != 0.f) {
        int tok = slot_tok[slot];
        float* op = out + (size_t)tok * DDIM + ecol;
#pragma unroll
        for (int ni = 0; ni < 4; ++ni)
          atomicAdd(op + ni * 16, w * acc[mi][ni][r]);
      }
    }
}

extern "C" void kernel_launch(void* const* d_in, const int* in_sizes, int n_in,
                              void* d_out, int out_size, void* d_ws, size_t ws_size,
                              hipStream_t stream) {
  const float* x = (const float*)d_in[0];
  const float* wts = (const float*)d_in[1];
  const int* idx = (const int*)d_in[2];
  const float* gup = (const float*)d_in[3];
  const float* dwn = (const float*)d_in[4];
  const float* scale = (const float*)d_in[5];
  float* out = (float*)d_out;

  char* ws = (char*)d_ws;
  f16* gup_t = (f16*)(ws + GUPT_OFF);
  f16* down_t = (f16*)(ws + DWNT_OFF);
  f16* xf = (f16*)(ws + XF_OFF);
  f16* act = (f16*)(ws + ACT_OFF);
  int* ctrl = (int*)(ws + CTRL_OFF);
  int* slot_tok = ctrl;
  float* slot_w = (float*)(ctrl + 9216);
  int* cnt = ctrl + 18432;
  int* cursor = ctrl + 18440;
  int* pad_off = ctrl + 18448;
  int* tile_e = ctrl + 18456;
  int* tile_r0 = ctrl + 18528;
  int* n_tiles = ctrl + 18600;
  int* is32 = ctrl + 18601;

  hipMemsetAsync(out, 0, (size_t)NTOK * DDIM * sizeof(float), stream);
  hipMemsetAsync(ctrl, 0, (size_t)CTRL_INTS * sizeof(int), stream);

  k_detect<<<NPAIR / 2 / 256, 256, 0, stream>>>(idx, is32);
  k_count<<<NPAIR / 256, 256, 0, stream>>>(idx, is32, cnt);
  k_plan<<<1, 1, 0, stream>>>(cnt, cursor, pad_off, tile_e, tile_r0, n_tiles);
  k_assign<<<NPAIR / 256, 256, 0, stream>>>(idx, is32, wts, scale, cursor, slot_tok, slot_w);
  k_cvt_x<<<NTOK * DDIM / 4 / 256, 256, 0, stream>>>(x, xf);
  k_transpose<<<dim3(4096 / 32, 2048 / 32, EXPERTS), dim3(32, 8), 0, stream>>>(gup, gup_t, 2048, 4096);
  k_transpose<<<dim3(2048 / 32, 2048 / 32, EXPERTS), dim3(32, 8), 0, stream>>>(dwn, down_t, 2048, 2048);
  k_gemm1<<<dim3(MAXTILE, HDIM / 128), 256, 0, stream>>>(xf, gup_t, slot_tok, tile_e, tile_r0, n_tiles, act);
  k_gemm2<<<dim3(MAXTILE, DDIM / 128), 256, 0, stream>>>(act, down_t, slot_tok, slot_w, tile_e, tile_r0, n_tiles, out);
}

// Round 2
// 607.152 us; speedup vs baseline: 1.2397x; 1.2397x over previous
//
#include <hip/hip_runtime.h>
#include <math.h>

// Problem constants
#define EXPERTS 8
#define DDIM 2048
#define HDIM 2048
#define NTOK 4096
#define NPAIR 8192
#define MAXSLOT 10240   // 8192 + 8*255 rounded up (256-padded per expert)
#define MAXTILE 40      // max sum of ceil(cnt_e/256) = 32 + 7

typedef _Float16 f16;
typedef __attribute__((ext_vector_type(8))) _Float16 f16x8;
typedef __attribute__((ext_vector_type(4))) float f32x4;

// ---- workspace layout (bytes); peak ~193 MB (< proven 244 MiB) ----
// Phase 1: gup_t f16 [E][4096][2048] at 0..128MB (transposed gate_up)
// Phase 2 (after GEMM1, gup_t dead): y f16 [MAXSLOT][2048] at 0..41.9MB,
//          down_t f16 [E][2048][2048] at 41.9..109MB
#define GUPT_OFF 0ull
#define Y_OFF    0ull
#define DWNT_OFF 41943040ull
#define XF_OFF   134217728ull    // f16 [NTOK][2048] = 16MB
#define ACT_OFF  150994944ull    // f16 [MAXSLOT][2048] = 41.9MB
#define CTRL_OFF 192937984ull
// ctrl (ints): slot_tok[10240]@0, tok_slot[8192]@10240, cnt[8]@18432,
// cursor[8]@18440, tile_e[40]@18448, tile_r0[40]@18488, n_tiles@18528,
// is32@18529, slot_w(float)[10240]@18536
#define CTRL_INTS 28776

#define BARRIER() asm volatile("s_barrier" ::: "memory")
#define VMCNT(n)  asm volatile("s_waitcnt vmcnt(" #n ")" ::: "memory")
#define LGKM0()   asm volatile("s_waitcnt lgkmcnt(0)" ::: "memory")

__device__ __forceinline__ void gload_lds16(const void* g, void* l) {
  __builtin_amdgcn_global_load_lds(
      (const __attribute__((address_space(1))) unsigned int*)g,
      (__attribute__((address_space(3))) unsigned int*)l,
      16, 0, 0);
}

// ---------------- routing ----------------
__global__ void k_detect(const int* __restrict__ w, int* flag) {
  int i = blockIdx.x * blockDim.x + threadIdx.x;
  if (i < NPAIR / 2 && w[2 * i + 1] != 0) atomicOr(flag, 1);
}

__device__ __forceinline__ int expert_of(const int* idx, int is32, int p) {
  return is32 ? idx[p] : idx[2 * p];
}

__global__ void k_count(const int* __restrict__ idx, const int* __restrict__ flag,
                        int* cnt) {
  int p = blockIdx.x * blockDim.x + threadIdx.x;
  if (p < NPAIR) atomicAdd(&cnt[expert_of(idx, *flag, p)], 1);
}

__global__ void k_plan(const int* __restrict__ cnt, int* cursor,
                       int* tile_e, int* tile_r0, int* n_tiles) {
  if (blockIdx.x == 0 && threadIdx.x == 0) {
    int off = 0, nt = 0;
    for (int e = 0; e < EXPERTS; ++e) {
      cursor[e] = off;
      int t = (cnt[e] + 255) >> 8;
      for (int i = 0; i < t; ++i) { tile_e[nt] = e; tile_r0[nt] = off + i * 256; ++nt; }
      off += t * 256;
    }
    *n_tiles = nt;
  }
}

__global__ void k_assign(const int* __restrict__ idx, const int* __restrict__ flag,
                         const float* __restrict__ wts, const float* __restrict__ scale,
                         int* cursor, int* slot_tok, int* tok_slot, float* slot_w) {
  int p = blockIdx.x * blockDim.x + threadIdx.x;
  if (p < NPAIR) {
    int e = expert_of(idx, *flag, p);
    int pos = atomicAdd(&cursor[e], 1);
    slot_tok[pos] = p >> 1;
    tok_slot[p] = pos;
    slot_w[pos] = wts[p] * scale[e];
  }
}

__global__ void k_cvt_x(const float* __restrict__ in, f16* __restrict__ out) {
  int i = blockIdx.x * blockDim.x + threadIdx.x;
  float4 v = ((const float4*)in)[i];
  typedef __attribute__((ext_vector_type(4))) _Float16 f16x4;
  f16x4 o = {(f16)v.x, (f16)v.y, (f16)v.z, (f16)v.w};
  ((f16x4*)out)[i] = o;
}

// fp32 [R][C] -> f16 [C][R], per expert (blockIdx.z)
__global__ void k_transpose(const float* __restrict__ in, f16* __restrict__ out,
                            int R, int C) {
  __shared__ float t[32][33];
  const size_t base = (size_t)blockIdx.z * R * C;
  const float* ip = in + base;
  f16* op = out + base;
  int c0 = blockIdx.x * 32, r0 = blockIdx.y * 32;
  int tx = threadIdx.x, ty = threadIdx.y;
#pragma unroll
  for (int i = 0; i < 32; i += 8)
    t[ty + i][tx] = ip[(size_t)(r0 + ty + i) * C + c0 + tx];
  __syncthreads();
#pragma unroll
  for (int i = 0; i < 32; i += 8)
    op[(size_t)(c0 + ty + i) * R + r0 + tx] = (f16)t[tx][ty + i];
}

// ---------------- 256x256x64 8-phase grouped GEMM ----------------
// G1: A = gathered x rows, B = gup_t (half0 = gate strip, half1 = up strip),
//     epilogue: LDS exchange + exact gelu -> act f16.
// G0: A = act rows (direct),  B = down_t, epilogue: y f16.
template <int G1>
__global__ __launch_bounds__(512, 2) void k_gemm8(
    const f16* __restrict__ Asrc, const f16* __restrict__ Bsrc,
    const int* __restrict__ slot_tok,
    const int* __restrict__ tile_e, const int* __restrict__ tile_r0,
    const int* __restrict__ n_tiles, f16* __restrict__ dst) {
  __shared__ __align__(16) f16 smem[4][256 * 64];  // A0 A1 B0 B1, 128 KiB

  // bijective XCD swizzle (nwg divisible by 8)
  const int nbx = MAXTILE, nby = G1 ? 16 : 8;
  const int nwg = nbx * nby, q = nwg / 8;
  int oid = (int)(blockIdx.y * nbx + blockIdx.x);
  int nid = (oid % 8) * q + oid / 8;
  const int bx = nid % nbx, nt = nid / nbx;
  if (bx >= *n_tiles) return;
  const int e = tile_e[bx];
  const int m0 = tile_r0[bx];

  const int tid = threadIdx.x;
  const int lane = tid & 63;
  const int wv = tid >> 6;
  const int wr = wv >> 2;   // 0..1 : row half
  const int wcl = wv & 3;   // 0..3 : col quarter (64 cols)
  const int fr = lane & 15;
  const int fhi = lane >> 4;

  // staging source pointers [half][issue]
  const int rh = tid >> 3;  // 0..63
  const int cc = tid & 7;   // chunk in row
  const f16* aS[2][2];
  const f16* bS[2][2];
#pragma unroll
  for (int h = 0; h < 2; ++h)
#pragma unroll
    for (int i = 0; i < 2; ++i) {
      const int rl = h * 128 + i * 64 + rh;        // row in [0,256)
      const int sc = cc ^ (rl & 7);                 // inverse-swizzled src chunk
      size_t arow = G1 ? (size_t)slot_tok[m0 + rl] : (size_t)(m0 + rl);
      aS[h][i] = Asrc + arow * 2048 + sc * 8;
      size_t brow;
      if (G1) brow = (size_t)e * 4096 + (h ? 2048 : 0) + (size_t)nt * 128 + (i * 64 + rh);
      else    brow = (size_t)e * 2048 + (size_t)nt * 256 + h * 128 + i * 64 + rh;
      bS[h][i] = Bsrc + brow * 2048 + sc * 8;
    }

  auto stageA = [&](int buf, int kt, int h) {
    const size_t ko = (size_t)kt * 64;
#pragma unroll
    for (int i = 0; i < 2; ++i)
      gload_lds16(aS[h][i] + ko, &smem[buf][h * 8192 + (i * 512 + tid) * 8]);
  };
  auto stageB = [&](int buf, int kt, int h) {
    const size_t ko = (size_t)kt * 64;
#pragma unroll
    for (int i = 0; i < 2; ++i)
      gload_lds16(bS[h][i] + ko, &smem[2 + buf][h * 8192 + (i * 512 + tid) * 8]);
  };

  f32x4 acc[8][4];
#pragma unroll
  for (int i = 0; i < 8; ++i)
#pragma unroll
    for (int j = 0; j < 4; ++j) acc[i][j] = (f32x4){0.f, 0.f, 0.f, 0.f};

  // prologue: B(0), A(0), B(1); wait first 8 loads (B0+A0), 2 half-tiles in flight
  stageB(0, 0, 0); stageB(0, 0, 1);
  stageA(0, 0, 0); stageA(0, 0, 1);
  stageB(1, 1, 0); stageB(1, 1, 1);
  VMCNT(4);
  BARRIER();

  const int NT = 32;  // K/64
  for (int kt = 0; kt < NT; ++kt) {
    const int buf = kt & 1;
    const f16* As = &smem[buf][0];
    const f16* Bs = &smem[2 + buf][0];
    f16x8 bfr[4][2];
    f16x8 afr[2][2];
#pragma unroll
    for (int p = 0; p < 4; ++p) {
      if (p == 0) {
#pragma unroll
        for (int ci = 0; ci < 4; ++ci)
#pragma unroll
          for (int k0 = 0; k0 < 2; ++k0) {
            const int r = wcl * 64 + ci * 16 + fr;
            const int ck = k0 * 4 + fhi;
            bfr[ci][k0] = *(const f16x8*)&Bs[r * 64 + ((ck ^ (r & 7)) << 3)];
          }
      }
#pragma unroll
      for (int i = 0; i < 2; ++i)
#pragma unroll
        for (int k0 = 0; k0 < 2; ++k0) {
          const int r = wr * 128 + (p * 2 + i) * 16 + fr;
          const int ck = k0 * 4 + fhi;
          afr[i][k0] = *(const f16x8*)&As[r * 64 + ((ck ^ (r & 7)) << 3)];
        }
      // prefetch: A one K-tile ahead (other buf), B two ahead (this buf's B,
      // dead after this tile's p0).
      if (p == 0 && kt + 1 < NT) stageA(buf ^ 1, kt + 1, 0);
      if (p == 1 && kt + 1 < NT) stageA(buf ^ 1, kt + 1, 1);
      if (p == 2 && kt + 2 < NT) stageB(buf, kt + 2, 0);
      if (p == 3 && kt + 2 < NT) stageB(buf, kt + 2, 1);
      BARRIER();
      LGKM0();
      __builtin_amdgcn_sched_barrier(0);
      __builtin_amdgcn_s_setprio(1);
#pragma unroll
      for (int i = 0; i < 2; ++i)
#pragma unroll
        for (int ci = 0; ci < 4; ++ci)
#pragma unroll
          for (int k0 = 0; k0 < 2; ++k0)
            acc[p * 2 + i][ci] = __builtin_amdgcn_mfma_f32_16x16x32_f16(
                afr[i][k0], bfr[ci][k0], acc[p * 2 + i][ci], 0, 0, 0);
      __builtin_amdgcn_s_setprio(0);
      __builtin_amdgcn_sched_barrier(0);
      BARRIER();
    }
    if (kt + 1 < NT) {
      if (kt + 1 == NT - 1) { VMCNT(0); } else { VMCNT(4); }
      BARRIER();
    }
  }

  if (G1) {
    // exchange up-wave accs through LDS; gate waves apply exact gelu
    float* xbuf = (float*)&smem[0][0];  // [256][65] f32 = 66.6KB
#pragma unroll
    for (int rnd = 0; rnd < 2; ++rnd) {
      BARRIER();
      if (wcl == rnd + 2) {
#pragma unroll
        for (int ri = 0; ri < 8; ++ri)
#pragma unroll
          for (int ci = 0; ci < 4; ++ci)
#pragma unroll
            for (int rg = 0; rg < 4; ++rg)
              xbuf[(wr * 128 + ri * 16 + fhi * 4 + rg) * 65 + ci * 16 + fr] =
                  acc[ri][ci][rg];
      }
      BARRIER();
      if (wcl == rnd) {
#pragma unroll
        for (int ri = 0; ri < 8; ++ri)
#pragma unroll
          for (int ci = 0; ci < 4; ++ci)
#pragma unroll
            for (int rg = 0; rg < 4; ++rg) {
              const int row = ri * 16 + fhi * 4 + rg;
              const float u = xbuf[(wr * 128 + row) * 65 + ci * 16 + fr];
              const float g = acc[ri][ci][rg];
              const float a = 0.5f * g * (1.0f + erff(g * 0.70710678118654752f)) * u;
              dst[(size_t)(m0 + wr * 128 + row) * 2048 +
                  (size_t)nt * 128 + wcl * 64 + ci * 16 + fr] = (f16)a;
            }
      }
    }
  } else {
#pragma unroll
    for (int ri = 0; ri < 8; ++ri)
#pragma unroll
      for (int ci = 0; ci < 4; ++ci)
#pragma unroll
        for (int rg = 0; rg < 4; ++rg)
          dst[(size_t)(m0 + wr * 128 + ri * 16 + fhi * 4 + rg) * 2048 +
              (size_t)nt * 256 + wcl * 64 + ci * 16 + fr] = (f16)acc[ri][ci][rg];
  }
}

// out[tok] = w(s0)*y[s0] + w(s1)*y[s1]  (fully writes out; no memset needed)
__global__ void k_combine(const f16* __restrict__ y, const float* __restrict__ slot_w,
                          const int* __restrict__ tok_slot, float* __restrict__ out) {
  const int gid = blockIdx.x * blockDim.x + threadIdx.x;  // NTOK*256 threads
  const int tok = gid >> 8;
  const int c = (gid & 255) * 8;
  const int s0 = tok_slot[2 * tok], s1 = tok_slot[2 * tok + 1];
  const float w0 = slot_w[s0], w1 = slot_w[s1];
  const f16x8 v0 = *(const f16x8*)&y[(size_t)s0 * 2048 + c];
  const f16x8 v1 = *(const f16x8*)&y[(size_t)s1 * 2048 + c];
  float o[8];
#pragma unroll
  for (int j = 0; j < 8; ++j) o[j] = w0 * (float)v0[j] + w1 * (float)v1[j];
  float4* op = (float4*)&out[(size_t)tok * 2048 + c];
  op[0] = (float4){o[0], o[1], o[2], o[3]};
  op[1] = (float4){o[4], o[5], o[6], o[7]};
}

extern "C" void kernel_launch(void* const* d_in, const int* in_sizes, int n_in,
                              void* d_out, int out_size, void* d_ws, size_t ws_size,
                              hipStream_t stream) {
  const float* x = (const float*)d_in[0];
  const float* wts = (const float*)d_in[1];
  const int* idx = (const int*)d_in[2];
  const float* gup = (const float*)d_in[3];
  const float* dwn = (const float*)d_in[4];
  const float* scale = (const float*)d_in[5];
  float* out = (float*)d_out;

  char* ws = (char*)d_ws;
  f16* gup_t = (f16*)(ws + GUPT_OFF);
  f16* y = (f16*)(ws + Y_OFF);          // aliases gup_t (dead after GEMM1)
  f16* down_t = (f16*)(ws + DWNT_OFF);  // aliases gup_t tail (dead after GEMM1)
  f16* xf = (f16*)(ws + XF_OFF);
  f16* act = (f16*)(ws + ACT_OFF);
  int* ctrl = (int*)(ws + CTRL_OFF);
  int* slot_tok = ctrl;
  int* tok_slot = ctrl + 10240;
  int* cnt = ctrl + 18432;
  int* cursor = ctrl + 18440;
  int* tile_e = ctrl + 18448;
  int* tile_r0 = ctrl + 18488;
  int* n_tiles = ctrl + 18528;
  int* is32 = ctrl + 18529;
  float* slot_w = (float*)(ctrl + 18536);

  hipMemsetAsync(ctrl, 0, (size_t)CTRL_INTS * sizeof(int), stream);

  k_detect<<<NPAIR / 2 / 256, 256, 0, stream>>>(idx, is32);
  k_count<<<NPAIR / 256, 256, 0, stream>>>(idx, is32, cnt);
  k_plan<<<1, 1, 0, stream>>>(cnt, cursor, tile_e, tile_r0, n_tiles);
  k_assign<<<NPAIR / 256, 256, 0, stream>>>(idx, is32, wts, scale, cursor,
                                            slot_tok, tok_slot, slot_w);
  k_cvt_x<<<NTOK * DDIM / 4 / 256, 256, 0, stream>>>(x, xf);
  k_transpose<<<dim3(4096 / 32, 2048 / 32, EXPERTS), dim3(32, 8), 0, stream>>>(
      gup, gup_t, 2048, 4096);
  k_gemm8<1><<<dim3(MAXTILE, 16), 512, 0, stream>>>(xf, gup_t, slot_tok, tile_e,
                                                    tile_r0, n_tiles, act);
  // gup_t dead now; transpose down into its tail, y into its head
  k_transpose<<<dim3(2048 / 32, 2048 / 32, EXPERTS), dim3(32, 8), 0, stream>>>(
      dwn, down_t, 2048, 2048);
  k_gemm8<0><<<dim3(MAXTILE, 8), 512, 0, stream>>>(act, down_t, slot_tok, tile_e,
                                                   tile_r0, n_tiles, y);
  k_combine<<<NTOK, 256, 0, stream>>>(y, slot_w, tok_slot, out);
}

// Round 3
// 501.636 us; speedup vs baseline: 1.5005x; 1.2103x over previous
//
#include <hip/hip_runtime.h>
#include <math.h>

// Problem constants
#define EXPERTS 8
#define DDIM 2048
#define HDIM 2048
#define NTOK 4096
#define NPAIR 8192
#define MAXSLOT 10240   // 8192 + 8*127 rounded up (128-padded per expert)
#define MAXTILE 72      // max sum of ceil(cnt_e/128) = 64 + 8

typedef _Float16 f16;
typedef __attribute__((ext_vector_type(8))) _Float16 f16x8;
typedef __attribute__((ext_vector_type(4))) float f32x4;

// ---- workspace layout (bytes); peak ~193 MB ----
// Phase 1: gup_t f16 [E][4096][2048] at 0..128MB (transposed gate_up)
// Phase 2 (after GEMM1, gup_t dead): y f16 [MAXSLOT][2048] at 0..41.9MB,
//          down_t f16 [E][2048][2048] at 41.9..109MB
#define GUPT_OFF 0ull
#define Y_OFF    0ull
#define DWNT_OFF 41943040ull
#define XF_OFF   134217728ull    // f16 [NTOK][2048] = 16MB
#define ACT_OFF  150994944ull    // f16 [MAXSLOT][2048] = 41.9MB
#define CTRL_OFF 192937984ull
// ctrl (ints): slot_tok[10240]@0, tok_slot[8192]@10240, cnt[8]@18432,
// cursor[8]@18440, tile_e[72]@18448, tile_r0[72]@18520, n_tiles@18592,
// is32@18593, slot_w(float)[10240]@18600
#define CTRL_INTS 28840

#define BARRIER() asm volatile("s_barrier" ::: "memory")
#define VMCNT(n)  asm volatile("s_waitcnt vmcnt(" #n ")" ::: "memory")

__device__ __forceinline__ void gload_lds16(const void* g, void* l) {
  __builtin_amdgcn_global_load_lds(
      (const __attribute__((address_space(1))) unsigned int*)g,
      (__attribute__((address_space(3))) unsigned int*)l,
      16, 0, 0);
}

// ---------------- routing ----------------
__global__ void k_detect(const int* __restrict__ w, int* flag) {
  int i = blockIdx.x * blockDim.x + threadIdx.x;
  if (i < NPAIR / 2 && w[2 * i + 1] != 0) atomicOr(flag, 1);
}

__device__ __forceinline__ int expert_of(const int* idx, int is32, int p) {
  return is32 ? idx[p] : idx[2 * p];
}

__global__ void k_count(const int* __restrict__ idx, const int* __restrict__ flag,
                        int* cnt) {
  int p = blockIdx.x * blockDim.x + threadIdx.x;
  if (p < NPAIR) atomicAdd(&cnt[expert_of(idx, *flag, p)], 1);
}

__global__ void k_plan(const int* __restrict__ cnt, int* cursor,
                       int* tile_e, int* tile_r0, int* n_tiles) {
  if (blockIdx.x == 0 && threadIdx.x == 0) {
    int off = 0, nt = 0;
    for (int e = 0; e < EXPERTS; ++e) {
      cursor[e] = off;
      int t = (cnt[e] + 127) >> 7;
      for (int i = 0; i < t; ++i) { tile_e[nt] = e; tile_r0[nt] = off + i * 128; ++nt; }
      off += t * 128;
    }
    *n_tiles = nt;
  }
}

__global__ void k_assign(const int* __restrict__ idx, const int* __restrict__ flag,
                         const float* __restrict__ wts, const float* __restrict__ scale,
                         int* cursor, int* slot_tok, int* tok_slot, float* slot_w) {
  int p = blockIdx.x * blockDim.x + threadIdx.x;
  if (p < NPAIR) {
    int e = expert_of(idx, *flag, p);
    int pos = atomicAdd(&cursor[e], 1);
    slot_tok[pos] = p >> 1;
    tok_slot[p] = pos;
    slot_w[pos] = wts[p] * scale[e];
  }
}

__global__ void k_cvt_x(const float* __restrict__ in, f16* __restrict__ out) {
  int i = blockIdx.x * blockDim.x + threadIdx.x;
  float4 v = ((const float4*)in)[i];
  typedef __attribute__((ext_vector_type(4))) _Float16 f16x4;
  f16x4 o = {(f16)v.x, (f16)v.y, (f16)v.z, (f16)v.w};
  ((f16x4*)out)[i] = o;
}

// fp32 [R][C] -> f16 [C][R], per expert (blockIdx.z)
__global__ void k_transpose(const float* __restrict__ in, f16* __restrict__ out,
                            int R, int C) {
  __shared__ float t[32][33];
  const size_t base = (size_t)blockIdx.z * R * C;
  const float* ip = in + base;
  f16* op = out + base;
  int c0 = blockIdx.x * 32, r0 = blockIdx.y * 32;
  int tx = threadIdx.x, ty = threadIdx.y;
#pragma unroll
  for (int i = 0; i < 32; i += 8)
    t[ty + i][tx] = ip[(size_t)(r0 + ty + i) * C + c0 + tx];
  __syncthreads();
#pragma unroll
  for (int i = 0; i < 32; i += 8)
    op[(size_t)(c0 + ty + i) * R + r0 + tx] = (f16)t[tx][ty + i];
}

// ---------------- 128x128x64 relaxed-sync grouped GEMM ----------------
// 8 waves (2M x 4N), wave-out 64x32, acc[4][2] (32 VGPR), LDS 64KB -> 2 blk/CU.
// 2 barriers per K-tile; counted vmcnt(2) (never drains in main loop).
// G1: A = gathered x rows; B = gup_t strip (rows 0-63 gate, 64-127 up);
//     epilogue: LDS exchange + exact gelu -> act.
// G0: A = act rows (direct); B = down_t strip; epilogue -> y.
template <int G1>
__global__ __launch_bounds__(512, 4) void k_gemm(
    const f16* __restrict__ Asrc, const f16* __restrict__ Bsrc,
    const int* __restrict__ slot_tok,
    const int* __restrict__ tile_e, const int* __restrict__ tile_r0,
    const int* __restrict__ n_tiles, f16* __restrict__ dst) {
  __shared__ __align__(16) f16 smem[4][128 * 64];  // A0 A1 B0 B1 = 64 KiB

  // bijective XCD swizzle; bx-fastest so same-nt blocks share an XCD's L2
  const int nbx = MAXTILE, nby = G1 ? 32 : 16;
  const int nwg = nbx * nby, q = nwg / 8;
  int oid = (int)(blockIdx.y * nbx + blockIdx.x);
  int nid = (oid % 8) * q + oid / 8;
  const int bx = nid % nbx, nt = nid / nbx;
  if (bx >= *n_tiles) return;
  const int e = tile_e[bx];
  const int m0 = tile_r0[bx];

  const int tid = threadIdx.x;
  const int lane = tid & 63;
  const int wv = tid >> 6;
  const int wrM = wv >> 2;   // 0..1 : 64-row half
  const int wcl = wv & 3;    // 0..3 : 32-col strip
  const int fr = lane & 15;
  const int fhi = lane >> 4;

  // staging sources: call c covers rows [c*64, c*64+64); lane's 16B chunk is
  // inverse-swizzled at the SOURCE (LDS dest stays linear; reads re-swizzle).
  const f16* aS[2];
  const f16* bS[2];
#pragma unroll
  for (int c = 0; c < 2; ++c) {
    const int rl = c * 64 + (tid >> 3);
    const int sc = (tid & 7) ^ (rl & 7);
    size_t arow = G1 ? (size_t)slot_tok[m0 + rl] : (size_t)(m0 + rl);
    aS[c] = Asrc + arow * 2048 + sc * 8;
    size_t brow;
    if (G1) brow = (size_t)e * 4096 + (rl < 64 ? (size_t)nt * 64 + rl
                                               : (size_t)2048 + nt * 64 + (rl - 64));
    else    brow = (size_t)e * 2048 + (size_t)nt * 128 + rl;
    bS[c] = Bsrc + brow * 2048 + sc * 8;
  }

  auto stageA = [&](int buf, int kt) {
#pragma unroll
    for (int c = 0; c < 2; ++c)
      gload_lds16(aS[c] + (size_t)kt * 64, &smem[buf][c * 4096 + tid * 8]);
  };
  auto stageB = [&](int buf, int kt) {
#pragma unroll
    for (int c = 0; c < 2; ++c)
      gload_lds16(bS[c] + (size_t)kt * 64, &smem[2 + buf][c * 4096 + tid * 8]);
  };

  f32x4 acc[4][2];
#pragma unroll
  for (int i = 0; i < 4; ++i)
#pragma unroll
    for (int j = 0; j < 2; ++j) acc[i][j] = (f32x4){0.f, 0.f, 0.f, 0.f};

  // prologue: queue = [B0 B0 A0 A0 B1 B1]; vmcnt(2) completes B0,A0
  stageB(0, 0);
  stageA(0, 0);
  stageB(1, 1);
  VMCNT(2);
  BARRIER();

  const int NT = DDIM / 64;  // 32
  for (int kt = 0; kt < NT; ++kt) {
    const int buf = kt & 1;
    const f16* As = &smem[buf][0];
    const f16* Bs = &smem[2 + buf][0];
    if (kt + 1 < NT) stageA(buf ^ 1, kt + 1);  // A dbuf; region dead since kt-1

    f16x8 bfr[2][2];
#pragma unroll
    for (int ci = 0; ci < 2; ++ci)
#pragma unroll
      for (int k0 = 0; k0 < 2; ++k0) {
        const int r = wcl * 32 + ci * 16 + fr;
        bfr[ci][k0] = *(const f16x8*)&Bs[r * 64 + (((k0 * 4 + fhi) ^ (r & 7)) << 3)];
      }
    // window 1: bands 0-1 (B fully consumed into regs here)
#pragma unroll
    for (int b = 0; b < 2; ++b) {
      f16x8 af[2];
#pragma unroll
      for (int k0 = 0; k0 < 2; ++k0) {
        const int r = wrM * 64 + b * 16 + fr;
        af[k0] = *(const f16x8*)&As[r * 64 + (((k0 * 4 + fhi) ^ (r & 7)) << 3)];
      }
#pragma unroll
      for (int ci = 0; ci < 2; ++ci)
#pragma unroll
        for (int k0 = 0; k0 < 2; ++k0)
          acc[b][ci] = __builtin_amdgcn_mfma_f32_16x16x32_f16(af[k0], bfr[ci][k0],
                                                              acc[b][ci], 0, 0, 0);
    }
    BARRIER();  // all waves' B-reads done -> B region reusable
    if (kt + 2 < NT) stageB(buf, kt + 2);  // same-parity B buffer
    // window 2: bands 2-3
#pragma unroll
    for (int b = 2; b < 4; ++b) {
      f16x8 af[2];
#pragma unroll
      for (int k0 = 0; k0 < 2; ++k0) {
        const int r = wrM * 64 + b * 16 + fr;
        af[k0] = *(const f16x8*)&As[r * 64 + (((k0 * 4 + fhi) ^ (r & 7)) << 3)];
      }
#pragma unroll
      for (int ci = 0; ci < 2; ++ci)
#pragma unroll
        for (int k0 = 0; k0 < 2; ++k0)
          acc[b][ci] = __builtin_amdgcn_mfma_f32_16x16x32_f16(af[k0], bfr[ci][k0],
                                                              acc[b][ci], 0, 0, 0);
    }
    // boundary: next kt needs A(kt+1), B(kt+1) landed; B(kt+2) stays in flight
    if (kt + 2 < NT) { VMCNT(2); } else { VMCNT(0); }
    BARRIER();
  }

  if (G1) {
    // up waves (wcl>=2) pass acc through LDS; gate waves apply exact gelu
    float* xb = (float*)&smem[0][0];  // [128][68] f32 = 34.8KB
    if (wcl >= 2) {
#pragma unroll
      for (int b = 0; b < 4; ++b)
#pragma unroll
        for (int ci = 0; ci < 2; ++ci)
#pragma unroll
          for (int rg = 0; rg < 4; ++rg)
            xb[(wrM * 64 + b * 16 + fhi * 4 + rg) * 68 + (wcl - 2) * 32 + ci * 16 + fr] =
                acc[b][ci][rg];
    }
    BARRIER();
    if (wcl < 2) {
#pragma unroll
      for (int b = 0; b < 4; ++b)
#pragma unroll
        for (int ci = 0; ci < 2; ++ci)
#pragma unroll
          for (int rg = 0; rg < 4; ++rg) {
            const int row = wrM * 64 + b * 16 + fhi * 4 + rg;
            const int gc = wcl * 32 + ci * 16 + fr;
            const float u = xb[row * 68 + gc];
            const float g = acc[b][ci][rg];
            const float a = 0.5f * g * (1.0f + erff(g * 0.70710678118654752f)) * u;
            dst[(size_t)(m0 + row) * 2048 + (size_t)nt * 64 + gc] = (f16)a;
          }
    }
  } else {
#pragma unroll
    for (int b = 0; b < 4; ++b)
#pragma unroll
      for (int ci = 0; ci < 2; ++ci)
#pragma unroll
        for (int rg = 0; rg < 4; ++rg)
          dst[(size_t)(m0 + wrM * 64 + b * 16 + fhi * 4 + rg) * 2048 +
              (size_t)nt * 128 + wcl * 32 + ci * 16 + fr] = (f16)acc[b][ci][rg];
  }
}

// out[tok] = w(s0)*y[s0] + w(s1)*y[s1]  (fully writes out; no memset needed)
__global__ void k_combine(const f16* __restrict__ y, const float* __restrict__ slot_w,
                          const int* __restrict__ tok_slot, float* __restrict__ out) {
  const int gid = blockIdx.x * blockDim.x + threadIdx.x;
  const int tok = gid >> 8;
  const int c = (gid & 255) * 8;
  const int s0 = tok_slot[2 * tok], s1 = tok_slot[2 * tok + 1];
  const float w0 = slot_w[s0], w1 = slot_w[s1];
  const f16x8 v0 = *(const f16x8*)&y[(size_t)s0 * 2048 + c];
  const f16x8 v1 = *(const f16x8*)&y[(size_t)s1 * 2048 + c];
  float o[8];
#pragma unroll
  for (int j = 0; j < 8; ++j) o[j] = w0 * (float)v0[j] + w1 * (float)v1[j];
  float4* op = (float4*)&out[(size_t)tok * 2048 + c];
  op[0] = (float4){o[0], o[1], o[2], o[3]};
  op[1] = (float4){o[4], o[5], o[6], o[7]};
}

extern "C" void kernel_launch(void* const* d_in, const int* in_sizes, int n_in,
                              void* d_out, int out_size, void* d_ws, size_t ws_size,
                              hipStream_t stream) {
  const float* x = (const float*)d_in[0];
  const float* wts = (const float*)d_in[1];
  const int* idx = (const int*)d_in[2];
  const float* gup = (const float*)d_in[3];
  const float* dwn = (const float*)d_in[4];
  const float* scale = (const float*)d_in[5];
  float* out = (float*)d_out;

  char* ws = (char*)d_ws;
  f16* gup_t = (f16*)(ws + GUPT_OFF);
  f16* y = (f16*)(ws + Y_OFF);          // aliases gup_t (dead after GEMM1)
  f16* down_t = (f16*)(ws + DWNT_OFF);  // aliases gup_t tail (dead after GEMM1)
  f16* xf = (f16*)(ws + XF_OFF);
  f16* act = (f16*)(ws + ACT_OFF);
  int* ctrl = (int*)(ws + CTRL_OFF);
  int* slot_tok = ctrl;
  int* tok_slot = ctrl + 10240;
  int* cnt = ctrl + 18432;
  int* cursor = ctrl + 18440;
  int* tile_e = ctrl + 18448;
  int* tile_r0 = ctrl + 18520;
  int* n_tiles = ctrl + 18592;
  int* is32 = ctrl + 18593;
  float* slot_w = (float*)(ctrl + 18600);

  hipMemsetAsync(ctrl, 0, (size_t)CTRL_INTS * sizeof(int), stream);

  k_detect<<<NPAIR / 2 / 256, 256, 0, stream>>>(idx, is32);
  k_count<<<NPAIR / 256, 256, 0, stream>>>(idx, is32, cnt);
  k_plan<<<1, 1, 0, stream>>>(cnt, cursor, tile_e, tile_r0, n_tiles);
  k_assign<<<NPAIR / 256, 256, 0, stream>>>(idx, is32, wts, scale, cursor,
                                            slot_tok, tok_slot, slot_w);
  k_cvt_x<<<NTOK * DDIM / 4 / 256, 256, 0, stream>>>(x, xf);
  k_transpose<<<dim3(4096 / 32, 2048 / 32, EXPERTS), dim3(32, 8), 0, stream>>>(
      gup, gup_t, 2048, 4096);
  k_gemm<1><<<dim3(MAXTILE, 32), 512, 0, stream>>>(xf, gup_t, slot_tok, tile_e,
                                                   tile_r0, n_tiles, act);
  // gup_t dead now; transpose down into its tail, y into its head
  k_transpose<<<dim3(2048 / 32, 2048 / 32, EXPERTS), dim3(32, 8), 0, stream>>>(
      dwn, down_t, 2048, 2048);
  k_gemm<0><<<dim3(MAXTILE, 16), 512, 0, stream>>>(act, down_t, slot_tok, tile_e,
                                                   tile_r0, n_tiles, y);
  k_combine<<<NTOK, 256, 0, stream>>>(y, slot_w, tok_slot, out);
}